// Round 3
// baseline (1892.456 us; speedup 1.0000x reference)
//
#include <hip/hip_runtime.h>
#include <hip/hip_bf16.h>

typedef __bf16 bf16x8 __attribute__((ext_vector_type(8)));
typedef float f32x4 __attribute__((ext_vector_type(4)));
typedef unsigned short u16x8 __attribute__((ext_vector_type(8)));

__device__ __forceinline__ unsigned short f2bf(float f) {
    union { float f; unsigned int u; } v; v.f = f;
    unsigned int u = v.u;
    unsigned int lsb = (u >> 16) & 1u;
    u += 0x7fffu + lsb;
    return (unsigned short)(u >> 16);
}
__device__ __forceinline__ float bf2f(unsigned short h) {
    union { unsigned int u; float f; } v; v.u = ((unsigned int)h) << 16;
    return v.f;
}
__device__ __forceinline__ void load8f(const float* p, float* a) {
    float4 v0 = *reinterpret_cast<const float4*>(p);
    float4 v1 = *reinterpret_cast<const float4*>(p + 4);
    a[0] = v0.x; a[1] = v0.y; a[2] = v0.z; a[3] = v0.w;
    a[4] = v1.x; a[5] = v1.y; a[6] = v1.z; a[7] = v1.w;
}

// ---------------- split-precision fp32 GEMM via bf16 MFMA ----------------
// C = scale*(A@B) + bias. A fp32 (staged as bf16 hi/lo pair). B fp32-split
// (BSPLIT=1, 3 MFMAs: ah*bh + ah*bl + al*bh) or plain bf16 (BSPLIT=0,
// 2 MFMAs: ah*b + al*b).
// AMODE: 0 = k-contiguous (lda_k==1), 1 = m-contiguous (lda_m==1)
// BMODE: 0 = k-contiguous (ldb_k==1), 1 = n-contiguous (ldb_n==1)
// QKV_EPI: 3-way column-split epilogue (Q f32 / K f32 / V bf16), bias = bqkv.
// Tile 64x64, BK=32, 4 waves.
template<int AMODE, int BMODE, bool BSPLIT, bool HAS_BIAS, bool QKV_EPI>
__global__ __launch_bounds__(256)
void gemm_split(const float* __restrict__ A, const void* __restrict__ Bp,
                const float* __restrict__ bias, float* __restrict__ C,
                float* __restrict__ Qp, float* __restrict__ Kp,
                unsigned short* __restrict__ Vp,
                int K,
                long long lda_m, long long lda_k, long long sAb,
                long long ldb_k, long long ldb_n, long long sBb,
                long long ldc, long long sCb, float scale)
{
    __shared__ __align__(16) unsigned short Ah[64][40], Al[64][40];
    __shared__ __align__(16) unsigned short Bh[64][40];
    __shared__ __align__(16) unsigned short Bl[BSPLIT ? 64 : 1][BSPLIT ? 40 : 1];

    const int tid  = threadIdx.x;
    const int wave = tid >> 6, lane = tid & 63;
    const int m0 = blockIdx.y * 64, n0 = blockIdx.x * 64;
    const int bz = blockIdx.z;
    const float* Ab = A + sAb * bz;
    const int wm = (wave >> 1) * 32, wn = (wave & 1) * 32;
    const int row = lane & 15, kq = (lane >> 4) * 8;

    f32x4 acc[2][2] = {};

    for (int k0 = 0; k0 < K; k0 += 32) {
        float a[8];
        // ---- stage A tile (64 m x 32 k) as hi/lo ----
        if (AMODE == 0) {
            int m = tid >> 2, c = (tid & 3) * 8;
            load8f(Ab + (long long)(m0 + m) * lda_m + (k0 + c), a);
            #pragma unroll
            for (int j = 0; j < 8; ++j) {
                unsigned short h = f2bf(a[j]);
                Ah[m][c + j] = h;
                Al[m][c + j] = f2bf(a[j] - bf2f(h));
            }
        } else {
            int k = tid >> 3, mc = (tid & 7) * 8;
            load8f(Ab + (long long)(k0 + k) * lda_k + (m0 + mc), a);
            #pragma unroll
            for (int j = 0; j < 8; ++j) {
                unsigned short h = f2bf(a[j]);
                Ah[mc + j][k] = h;
                Al[mc + j][k] = f2bf(a[j] - bf2f(h));
            }
        }
        // ---- stage B tile as Bs[n][k] (transposed) ----
        if (BSPLIT) {
            const float* Bb = (const float*)Bp + sBb * bz;
            if (BMODE == 0) {
                int n = tid >> 2, c = (tid & 3) * 8;
                load8f(Bb + (long long)(n0 + n) * ldb_n + (k0 + c), a);
                #pragma unroll
                for (int j = 0; j < 8; ++j) {
                    unsigned short h = f2bf(a[j]);
                    Bh[n][c + j] = h;
                    Bl[n][c + j] = f2bf(a[j] - bf2f(h));
                }
            } else {
                int k = tid >> 3, nc = (tid & 7) * 8;
                load8f(Bb + (long long)(k0 + k) * ldb_k + (n0 + nc), a);
                #pragma unroll
                for (int j = 0; j < 8; ++j) {
                    unsigned short h = f2bf(a[j]);
                    Bh[nc + j][k] = h;
                    Bl[nc + j][k] = f2bf(a[j] - bf2f(h));
                }
            }
        } else {
            const unsigned short* Bb = (const unsigned short*)Bp + sBb * bz;
            if (BMODE == 0) {
                int n = tid >> 2, c = (tid & 3) * 8;
                u16x8 v = *reinterpret_cast<const u16x8*>(Bb + (long long)(n0 + n) * ldb_n + (k0 + c));
                *reinterpret_cast<u16x8*>(&Bh[n][c]) = v;
            } else {
                int k = tid >> 3, nc = (tid & 7) * 8;
                u16x8 v = *reinterpret_cast<const u16x8*>(Bb + (long long)(k0 + k) * ldb_k + (n0 + nc));
                #pragma unroll
                for (int j = 0; j < 8; ++j) Bh[nc + j][k] = v[j];
            }
        }
        __syncthreads();

        bf16x8 afh[2], afl[2], bfh[2], bfl[2];
        #pragma unroll
        for (int mi = 0; mi < 2; ++mi) {
            afh[mi] = *reinterpret_cast<const bf16x8*>(&Ah[wm + mi * 16 + row][kq]);
            afl[mi] = *reinterpret_cast<const bf16x8*>(&Al[wm + mi * 16 + row][kq]);
        }
        #pragma unroll
        for (int ni = 0; ni < 2; ++ni) {
            bfh[ni] = *reinterpret_cast<const bf16x8*>(&Bh[wn + ni * 16 + row][kq]);
            if (BSPLIT) bfl[ni] = *reinterpret_cast<const bf16x8*>(&Bl[wn + ni * 16 + row][kq]);
        }
        #pragma unroll
        for (int mi = 0; mi < 2; ++mi)
            #pragma unroll
            for (int ni = 0; ni < 2; ++ni) {
                acc[mi][ni] = __builtin_amdgcn_mfma_f32_16x16x32_bf16(afl[mi], bfh[ni], acc[mi][ni], 0, 0, 0);
                if (BSPLIT)
                    acc[mi][ni] = __builtin_amdgcn_mfma_f32_16x16x32_bf16(afh[mi], bfl[ni], acc[mi][ni], 0, 0, 0);
                acc[mi][ni] = __builtin_amdgcn_mfma_f32_16x16x32_bf16(afh[mi], bfh[ni], acc[mi][ni], 0, 0, 0);
            }
        __syncthreads();
    }

    // ---- epilogue: D[row=(lane>>4)*4+r][col=lane&15] ----
    #pragma unroll
    for (int mi = 0; mi < 2; ++mi) {
        int r0 = m0 + wm + mi * 16 + (lane >> 4) * 4;
        #pragma unroll
        for (int ni = 0; ni < 2; ++ni) {
            int c = n0 + wn + ni * 16 + (lane & 15);
            float bv = (HAS_BIAS || QKV_EPI) ? bias[c] : 0.0f;
            #pragma unroll
            for (int r = 0; r < 4; ++r) {
                float v = acc[mi][ni][r] * scale + bv;
                long long m = r0 + r;
                if (QKV_EPI) {
                    int seg = c >> 10, lc = c & 1023;       // wave-uniform seg per block
                    long long idx = m * 1024 + lc;
                    if (seg == 0)      Qp[idx] = v;
                    else if (seg == 1) Kp[idx] = v;
                    else               Vp[idx] = f2bf(v);
                } else {
                    C[sCb * bz + m * ldc + c] = v;
                }
            }
        }
    }
}

// ---------------- row softmax: 1024 fp32 -> 1024 fp32 (in-place safe) ----------------
__global__ __launch_bounds__(256)
void softmax_rows_1024(const float* __restrict__ in, float* __restrict__ out)
{
    const int tid = threadIdx.x;
    const int wave = tid >> 6, lane = tid & 63;
    const long long rowoff = (long long)blockIdx.x * 1024;
    float4 v = reinterpret_cast<const float4*>(in + rowoff)[tid];

    float mx = fmaxf(fmaxf(v.x, v.y), fmaxf(v.z, v.w));
    #pragma unroll
    for (int o = 32; o > 0; o >>= 1) mx = fmaxf(mx, __shfl_xor(mx, o));
    __shared__ float rmax[4];
    if (lane == 0) rmax[wave] = mx;
    __syncthreads();
    mx = fmaxf(fmaxf(rmax[0], rmax[1]), fmaxf(rmax[2], rmax[3]));

    float e0 = expf(v.x - mx), e1 = expf(v.y - mx), e2 = expf(v.z - mx), e3 = expf(v.w - mx);
    float s = e0 + e1 + e2 + e3;
    #pragma unroll
    for (int o = 32; o > 0; o >>= 1) s += __shfl_xor(s, o);
    __shared__ float rsum[4];
    if (lane == 0) rsum[wave] = s;
    __syncthreads();
    s = rsum[0] + rsum[1] + rsum[2] + rsum[3];
    float inv = 1.0f / s;

    reinterpret_cast<float4*>(out + rowoff)[tid] =
        make_float4(e0 * inv, e1 * inv, e2 * inv, e3 * inv);
}

extern "C" void kernel_launch(void* const* d_in, const int* in_sizes, int n_in,
                              void* d_out, int out_size, void* d_ws, size_t ws_size,
                              hipStream_t stream)
{
    const float* x    = (const float*)d_in[0];  // (4,4096,1024)
    const float* Wqkv = (const float*)d_in[1];  // (1024,3072)
    const float* bqkv = (const float*)d_in[2];  // (3072,)
    const float* Wout = (const float*)d_in[3];  // (1024,1024)
    const float* bout = (const float*)d_in[4];  // (1024,)
    float* out = (float*)d_out;                 // (4,4096,1024) fp32

    // ---- workspace layout (peak 184,549,376 B < 201.3 MB proven-safe) ----
    char* ws = (char*)d_ws;
    float*          Qp   = (float*)(ws);                    // 67,108,864 B (4,4096,1024) f32
    float*          Kp   = (float*)(ws + 67108864);         // 67,108,864 B
    unsigned short* Vp   = (unsigned short*)(ws + 134217728); // 33,554,432 B bf16
    float*          dots = (float*)(ws + 167772160);        // 16,777,216 B (4,1024,1024)
    float*          omid = (float*)(ws);                    // overlays Qp (Q dead after GEMM2)

    // 1) qkv = x @ Wqkv + bqkv -> Q f32, K f32, V bf16  (M=16384, N=3072, K=1024)
    gemm_split<0, 1, true, true, true><<<dim3(48, 256, 1), dim3(256), 0, stream>>>(
        x, Wqkv, bqkv, nullptr, Qp, Kp, Vp, 1024,
        1024LL, 1LL, 0LL,
        3072LL, 1LL, 0LL,
        0LL, 0LL, 1.0f);

    // 2) dots[b][f][g] = 0.125 * sum_n Q[b][n][f] K[b][n][g]  (M=N=1024, K=4096)
    gemm_split<1, 1, true, false, false><<<dim3(16, 16, 4), dim3(256), 0, stream>>>(
        Qp, Kp, nullptr, dots, nullptr, nullptr, nullptr, 4096,
        1LL, 1024LL, 4194304LL,
        1024LL, 1LL, 4194304LL,
        1024LL, 1048576LL, 0.125f);

    // 3) softmax over g (in-place)
    softmax_rows_1024<<<dim3(4096), dim3(256), 0, stream>>>(dots, dots);

    // 4) omid[b][f][n] = sum_g attn[b][f][g] V[b][n][g]  (M=1024, N=4096, K=1024), B bf16
    gemm_split<0, 0, false, false, false><<<dim3(64, 16, 4), dim3(256), 0, stream>>>(
        dots, Vp, nullptr, omid, nullptr, nullptr, nullptr, 1024,
        1024LL, 1LL, 1048576LL,
        1LL, 1024LL, 4194304LL,
        4096LL, 4194304LL, 1.0f);

    // 5) out = omid_flat(16384x1024) @ Wout + bout  (flat reinterpret is free)
    gemm_split<0, 1, true, true, false><<<dim3(16, 256, 1), dim3(256), 0, stream>>>(
        omid, Wout, bout, out, nullptr, nullptr, nullptr, 1024,
        1024LL, 1LL, 0LL,
        1024LL, 1LL, 0LL,
        1024LL, 0LL, 1.0f);
}

// Round 4
// 1056.124 us; speedup vs baseline: 1.7919x; 1.7919x over previous
//
#include <hip/hip_runtime.h>
#include <hip/hip_bf16.h>

typedef __bf16 bf16x8 __attribute__((ext_vector_type(8)));
typedef float f32x4 __attribute__((ext_vector_type(4)));
typedef unsigned short u16x4 __attribute__((ext_vector_type(4)));
typedef unsigned short u16x8 __attribute__((ext_vector_type(8)));

__device__ __forceinline__ unsigned short f2bf(float f) {
    union { float f; unsigned int u; } v; v.f = f;
    unsigned int u = v.u;
    unsigned int lsb = (u >> 16) & 1u;
    u += 0x7fffu + lsb;
    return (unsigned short)(u >> 16);
}
__device__ __forceinline__ float bf2f(unsigned short h) {
    union { unsigned int u; float f; } v; v.u = ((unsigned int)h) << 16;
    return v.f;
}

// async global->LDS, 16B per lane. LDS dest = wave-uniform base + lane*16.
__device__ __forceinline__ void gload16(const void* g, void* s) {
    __builtin_amdgcn_global_load_lds((const __attribute__((address_space(1))) void*)g,
                                     (__attribute__((address_space(3))) void*)s, 16, 0, 0);
}

// ---------------- x fp32 -> hi/lo bf16 planes ----------------
__global__ __launch_bounds__(256)
void split_f32(const float* __restrict__ in, unsigned short* __restrict__ hi,
               unsigned short* __restrict__ lo, int n8) {
    int i = blockIdx.x * 256 + threadIdx.x, st = gridDim.x * 256;
    for (; i < n8; i += st) {
        float4 v0 = reinterpret_cast<const float4*>(in)[2 * i];
        float4 v1 = reinterpret_cast<const float4*>(in)[2 * i + 1];
        float a[8] = {v0.x, v0.y, v0.z, v0.w, v1.x, v1.y, v1.z, v1.w};
        u16x8 h, l;
        #pragma unroll
        for (int j = 0; j < 8; ++j) {
            unsigned short hh = f2bf(a[j]);
            h[j] = hh; l[j] = f2bf(a[j] - bf2f(hh));
        }
        reinterpret_cast<u16x8*>(hi)[i] = h;
        reinterpret_cast<u16x8*>(lo)[i] = l;
    }
}

// ---------------- W (R x C fp32) -> W^T hi/lo bf16 (C x R) ----------------
__global__ __launch_bounds__(256)
void transpose_split(const float* __restrict__ in, unsigned short* __restrict__ oh,
                     unsigned short* __restrict__ ol, int R, int C) {
    __shared__ float T[64][65];
    const int r0 = blockIdx.y * 64, c0 = blockIdx.x * 64;
    const int t = threadIdx.x;
    const int lr = t >> 2, lcq = (t & 3) * 16;
    #pragma unroll
    for (int q = 0; q < 4; ++q) {
        float4 v = *reinterpret_cast<const float4*>(&in[(long long)(r0 + lr) * C + c0 + lcq + q * 4]);
        T[lr][lcq + q * 4 + 0] = v.x; T[lr][lcq + q * 4 + 1] = v.y;
        T[lr][lcq + q * 4 + 2] = v.z; T[lr][lcq + q * 4 + 3] = v.w;
    }
    __syncthreads();
    const int oc = t >> 2, orq = (t & 3) * 16;
    #pragma unroll
    for (int q = 0; q < 4; ++q) {
        u16x4 hv, lv;
        #pragma unroll
        for (int j = 0; j < 4; ++j) {
            float a = T[orq + q * 4 + j][oc];
            unsigned short h = f2bf(a);
            hv[j] = h; lv[j] = f2bf(a - bf2f(h));
        }
        long long o = (long long)(c0 + oc) * R + r0 + orq + q * 4;
        *reinterpret_cast<u16x4*>(&oh[o]) = hv;
        *reinterpret_cast<u16x4*>(&ol[o]) = lv;
    }
}

// ---------------- m97-style bf16 GEMM: C = scale * sum_p A_p @ B_p^T (+bias) ----------------
// A_p[M][K] lda, Bt_p[N][K] ldb, both k-contiguous bf16.
// 128x128 tile, BK=32, 256 thr / 4 waves, wave -> 64x64 quadrant (4x4 of 16x16x32).
// EPI: 0 = f32 out (scale)          1 = f32 out + bias
//      2 = bf16 out                 3 = QKV (bias; Q^T,K^T hi/lo pairs + V bf16)
template<int NPAIR, int EPI>
__global__ __launch_bounds__(256)
void gemm_bt(const unsigned short* __restrict__ A0, const unsigned short* __restrict__ A1,
             const unsigned short* __restrict__ A2,
             const unsigned short* __restrict__ B0, const unsigned short* __restrict__ B1,
             const unsigned short* __restrict__ B2,
             int K, long long lda, long long ldb,
             long long sA, long long sB, long long sC,
             float* __restrict__ Cf, unsigned short* __restrict__ Cbf, long long ldc,
             const float* __restrict__ bias, float scale,
             unsigned short* __restrict__ qth, unsigned short* __restrict__ qtl,
             unsigned short* __restrict__ kth, unsigned short* __restrict__ ktl,
             unsigned short* __restrict__ vout)
{
    __shared__ __align__(16) unsigned short As[128][32];
    __shared__ __align__(16) unsigned short Bs[128][32];

    const int tid  = threadIdx.x;
    const int wave = tid >> 6, lane = tid & 63;
    const int m0 = blockIdx.y * 128, n0 = blockIdx.x * 128;
    const int bz = blockIdx.z;
    const int wm = (wave >> 1) * 64, wn = (wave & 1) * 64;
    const int fr = lane & 15, kq = (lane >> 4) * 8;
    const int srow = lane >> 2, scol = (lane & 3) * 8;   // staging coords

    f32x4 acc[4][4] = {};

    #pragma unroll
    for (int p = 0; p < NPAIR; ++p) {
        const unsigned short* Ag = (p == 0 ? A0 : p == 1 ? A1 : A2) + sA * bz + (long long)m0 * lda;
        const unsigned short* Bg = (p == 0 ? B0 : p == 1 ? B1 : B2) + sB * bz + (long long)n0 * ldb;
        for (int k0 = 0; k0 < K; k0 += 32) {
            #pragma unroll
            for (int i = 0; i < 2; ++i) {
                int r = i * 64 + wave * 16 + srow;
                gload16(Ag + (long long)r * lda + k0 + scol,
                        (char*)&As[0][0] + i * 4096 + wave * 1024);
                gload16(Bg + (long long)r * ldb + k0 + scol,
                        (char*)&Bs[0][0] + i * 4096 + wave * 1024);
            }
            __syncthreads();   // compiler drains vmcnt before barrier
            bf16x8 af[4], bf[4];
            #pragma unroll
            for (int t = 0; t < 4; ++t) {
                af[t] = *reinterpret_cast<const bf16x8*>(&As[wm + t * 16 + fr][kq]);
                bf[t] = *reinterpret_cast<const bf16x8*>(&Bs[wn + t * 16 + fr][kq]);
            }
            #pragma unroll
            for (int mi = 0; mi < 4; ++mi)
                #pragma unroll
                for (int ni = 0; ni < 4; ++ni)
                    acc[mi][ni] = __builtin_amdgcn_mfma_f32_16x16x32_bf16(af[mi], bf[ni], acc[mi][ni], 0, 0, 0);
            __syncthreads();
        }
    }

    // epilogue: D[row=(lane>>4)*4+rr][col=lane&15]
    const int rb = (lane >> 4) * 4;
    #pragma unroll
    for (int mi = 0; mi < 4; ++mi) {
        const int rloc = wm + mi * 16 + rb;
        #pragma unroll
        for (int ni = 0; ni < 4; ++ni) {
            const int c = n0 + wn + ni * 16 + fr;
            float bv = (EPI == 1 || EPI == 3) ? bias[c] : 0.0f;
            float v[4];
            #pragma unroll
            for (int rr = 0; rr < 4; ++rr) v[rr] = acc[mi][ni][rr] * scale + bv;

            if (EPI == 0 || EPI == 1) {
                long long base = sC * bz + (long long)(m0 + rloc) * ldc + c;
                #pragma unroll
                for (int rr = 0; rr < 4; ++rr) Cf[base + (long long)rr * ldc] = v[rr];
            } else if (EPI == 2) {
                long long base = sC * bz + (long long)(m0 + rloc) * ldc + c;
                #pragma unroll
                for (int rr = 0; rr < 4; ++rr) Cbf[base + (long long)rr * ldc] = f2bf(v[rr]);
            } else {
                const int m = m0 + rloc;          // 0..8191 (2-batch chunk)
                const int bloc = m >> 12;         // local batch
                const int nb = m & 4095;
                const int seg = n0 >> 10;         // block-uniform: 0=Q 1=K 2=V
                const int lc = c & 1023;
                if (seg == 2) {
                    #pragma unroll
                    for (int rr = 0; rr < 4; ++rr)
                        vout[(long long)bloc * 4194304 + (long long)(nb + rr) * 1024 + lc] = f2bf(v[rr]);
                } else {
                    u16x4 hv, lv;
                    #pragma unroll
                    for (int rr = 0; rr < 4; ++rr) {
                        unsigned short h = f2bf(v[rr]);
                        hv[rr] = h; lv[rr] = f2bf(v[rr] - bf2f(h));
                    }
                    long long o = (long long)bloc * 4194304 + (long long)lc * 4096 + nb;
                    unsigned short* ph = (seg == 0) ? qth : kth;
                    unsigned short* pl = (seg == 0) ? qtl : ktl;
                    *reinterpret_cast<u16x4*>(&ph[o]) = hv;
                    *reinterpret_cast<u16x4*>(&pl[o]) = lv;
                }
            }
        }
    }
}

// ---------------- row softmax: 1024 fp32 -> 1024 bf16 ----------------
__global__ __launch_bounds__(256)
void softmax_rows_1024(const float* __restrict__ in, unsigned short* __restrict__ out)
{
    const int tid = threadIdx.x;
    const int wave = tid >> 6, lane = tid & 63;
    const long long rowoff = (long long)blockIdx.x * 1024;
    float4 v = reinterpret_cast<const float4*>(in + rowoff)[tid];

    float mx = fmaxf(fmaxf(v.x, v.y), fmaxf(v.z, v.w));
    #pragma unroll
    for (int o = 32; o > 0; o >>= 1) mx = fmaxf(mx, __shfl_xor(mx, o));
    __shared__ float rmax[4];
    if (lane == 0) rmax[wave] = mx;
    __syncthreads();
    mx = fmaxf(fmaxf(rmax[0], rmax[1]), fmaxf(rmax[2], rmax[3]));

    float e0 = expf(v.x - mx), e1 = expf(v.y - mx), e2 = expf(v.z - mx), e3 = expf(v.w - mx);
    float s = e0 + e1 + e2 + e3;
    #pragma unroll
    for (int o = 32; o > 0; o >>= 1) s += __shfl_xor(s, o);
    __shared__ float rsum[4];
    if (lane == 0) rsum[wave] = s;
    __syncthreads();
    s = rsum[0] + rsum[1] + rsum[2] + rsum[3];
    float inv = 1.0f / s;

    u16x4 o4;
    o4[0] = f2bf(e0 * inv); o4[1] = f2bf(e1 * inv);
    o4[2] = f2bf(e2 * inv); o4[3] = f2bf(e3 * inv);
    *reinterpret_cast<u16x4*>(out + rowoff + tid * 4) = o4;
}

extern "C" void kernel_launch(void* const* d_in, const int* in_sizes, int n_in,
                              void* d_out, int out_size, void* d_ws, size_t ws_size,
                              hipStream_t stream)
{
    const float* x    = (const float*)d_in[0];  // (4,4096,1024)
    const float* Wqkv = (const float*)d_in[1];  // (1024,3072)
    const float* bqkv = (const float*)d_in[2];  // (3072,)
    const float* Wout = (const float*)d_in[3];  // (1024,1024)
    const float* bout = (const float*)d_in[4];  // (1024,)
    float* out = (float*)d_out;                 // (4,4096,1024) fp32

    // ---- workspace (peak 201,326,592 B == round-1 proven) ----
    char* ws = (char*)d_ws;
    unsigned short* xh   = (unsigned short*)(ws);              // 33,554,432
    unsigned short* xl   = (unsigned short*)(ws + 33554432);   // 33,554,432
    unsigned short* Wqh  = (unsigned short*)(ws + 67108864);   //  6,291,456 (3072x1024)
    unsigned short* Wql  = (unsigned short*)(ws + 73400320);   //  6,291,456
    unsigned short* Woh  = (unsigned short*)(ws + 79691776);   //  2,097,152 (1024x1024)
    unsigned short* Wol  = (unsigned short*)(ws + 81788928);   //  2,097,152
    unsigned short* V    = (unsigned short*)(ws + 83886080);   // 33,554,432 (4,4096,1024) bf16
    unsigned short* Qth  = (unsigned short*)(ws + 117440512);  // 16,777,216 (2,1024,4096)
    unsigned short* Qtl  = (unsigned short*)(ws + 134217728);
    unsigned short* Kth  = (unsigned short*)(ws + 150994944);
    unsigned short* Ktl  = (unsigned short*)(ws + 167772160);
    float*          dots = (float*)(ws + 184549376);           // 16,777,216 (4,1024,1024) f32
    unsigned short* attn = (unsigned short*)(ws);              //  8,388,608 (overlays xh; x dead)
    unsigned short* omid = (unsigned short*)(ws + 8388608);    // 33,554,432 (overlays x; x dead)

    // converts
    split_f32<<<dim3(2048), dim3(256), 0, stream>>>(x, xh, xl, 2097152);
    transpose_split<<<dim3(48, 16), dim3(256), 0, stream>>>(Wqkv, Wqh, Wql, 1024, 3072);
    transpose_split<<<dim3(16, 16), dim3(256), 0, stream>>>(Wout, Woh, Wol, 1024, 1024);

    for (int c = 0; c < 2; ++c) {
        // 1) qkv chunk: (xh,Wh)+(xl,Wh)+(xh,Wl) -> Q^T/K^T hi+lo pairs, V bf16
        gemm_bt<3, 3><<<dim3(24, 64, 1), dim3(256), 0, stream>>>(
            xh + c * 8388608, xl + c * 8388608, xh + c * 8388608,
            Wqh, Wqh, Wql,
            1024, 1024LL, 1024LL, 0LL, 0LL, 0LL,
            nullptr, nullptr, 0LL, bqkv, 1.0f,
            Qth, Qtl, Kth, Ktl, V + c * 8388608);

        // 2) dots chunk: (Qh,Kh)+(Ql,Kh)+(Qh,Kl), K=4096, per local batch z
        gemm_bt<3, 0><<<dim3(8, 8, 2), dim3(256), 0, stream>>>(
            Qth, Qtl, Qth,
            Kth, Kth, Ktl,
            4096, 4096LL, 4096LL, 4194304LL, 4194304LL, 1048576LL,
            dots + c * 2097152, nullptr, 1024LL, nullptr, 0.125f,
            nullptr, nullptr, nullptr, nullptr, nullptr);
    }

    // 3) softmax (all 4096 rows) -> attn bf16
    softmax_rows_1024<<<dim3(4096), dim3(256), 0, stream>>>(dots, attn);

    // 4) omid[b][f][n] = attn[b] @ V[b]^T  (M=1024, N=4096, K=1024) -> bf16
    gemm_bt<1, 2><<<dim3(32, 8, 4), dim3(256), 0, stream>>>(
        attn, nullptr, nullptr,
        V, nullptr, nullptr,
        1024, 1024LL, 1024LL, 1048576LL, 4194304LL, 4194304LL,
        nullptr, omid, 4096LL, nullptr, 1.0f,
        nullptr, nullptr, nullptr, nullptr, nullptr);

    // 5) out = omid_flat(16384x1024) @ Wout + bout: (omid,Woh)+(omid,Wol) -> f32
    gemm_bt<2, 1><<<dim3(8, 128, 1), dim3(256), 0, stream>>>(
        omid, omid, nullptr,
        Woh, Wol, nullptr,
        1024, 1024LL, 1024LL, 0LL, 0LL, 0LL,
        out, nullptr, 1024LL, bout, 1.0f,
        nullptr, nullptr, nullptr, nullptr, nullptr);
}

// Round 6
// 623.956 us; speedup vs baseline: 3.0330x; 1.6926x over previous
//
#include <hip/hip_runtime.h>
#include <hip/hip_bf16.h>

typedef __bf16 bf16x8 __attribute__((ext_vector_type(8)));
typedef float f32x4 __attribute__((ext_vector_type(4)));
typedef unsigned short u16x4 __attribute__((ext_vector_type(4)));
typedef unsigned short u16x8 __attribute__((ext_vector_type(8)));

__device__ __forceinline__ unsigned short f2bf(float f) {
    union { float f; unsigned int u; } v; v.f = f;
    unsigned int u = v.u;
    unsigned int lsb = (u >> 16) & 1u;
    u += 0x7fffu + lsb;
    return (unsigned short)(u >> 16);
}
__device__ __forceinline__ float bf2f(unsigned short h) {
    union { unsigned int u; float f; } v; v.u = ((unsigned int)h) << 16;
    return v.f;
}

// async global->LDS, 16B per lane. LDS dest = wave-uniform base + lane*16.
__device__ __forceinline__ void gload16(const void* g, void* s) {
    __builtin_amdgcn_global_load_lds((const __attribute__((address_space(1))) void*)g,
                                     (__attribute__((address_space(3))) void*)s, 16, 0, 0);
}

// ---------------- zero fp32 buffer ----------------
__global__ __launch_bounds__(256)
void zero_f32(float* __restrict__ p, int n4) {
    int i = blockIdx.x * 256 + threadIdx.x, st = gridDim.x * 256;
    for (; i < n4; i += st)
        reinterpret_cast<float4*>(p)[i] = make_float4(0.f, 0.f, 0.f, 0.f);
}

// ---------------- x fp32 -> hi/lo bf16 planes ----------------
__global__ __launch_bounds__(256)
void split_f32(const float* __restrict__ in, unsigned short* __restrict__ hi,
               unsigned short* __restrict__ lo, int n8) {
    int i = blockIdx.x * 256 + threadIdx.x, st = gridDim.x * 256;
    for (; i < n8; i += st) {
        float4 v0 = reinterpret_cast<const float4*>(in)[2 * i];
        float4 v1 = reinterpret_cast<const float4*>(in)[2 * i + 1];
        float a[8] = {v0.x, v0.y, v0.z, v0.w, v1.x, v1.y, v1.z, v1.w};
        u16x8 h, l;
        #pragma unroll
        for (int j = 0; j < 8; ++j) {
            unsigned short hh = f2bf(a[j]);
            h[j] = hh; l[j] = f2bf(a[j] - bf2f(hh));
        }
        reinterpret_cast<u16x8*>(hi)[i] = h;
        reinterpret_cast<u16x8*>(lo)[i] = l;
    }
}

// ---------------- W (R x C fp32) -> W^T hi/lo bf16 (C x R) ----------------
__global__ __launch_bounds__(256)
void transpose_split(const float* __restrict__ in, unsigned short* __restrict__ oh,
                     unsigned short* __restrict__ ol, int R, int C) {
    __shared__ float T[64][65];
    const int r0 = blockIdx.y * 64, c0 = blockIdx.x * 64;
    const int t = threadIdx.x;
    const int lr = t >> 2, lcq = (t & 3) * 16;
    #pragma unroll
    for (int q = 0; q < 4; ++q) {
        float4 v = *reinterpret_cast<const float4*>(&in[(long long)(r0 + lr) * C + c0 + lcq + q * 4]);
        T[lr][lcq + q * 4 + 0] = v.x; T[lr][lcq + q * 4 + 1] = v.y;
        T[lr][lcq + q * 4 + 2] = v.z; T[lr][lcq + q * 4 + 3] = v.w;
    }
    __syncthreads();
    const int oc = t >> 2, orq = (t & 3) * 16;
    #pragma unroll
    for (int q = 0; q < 4; ++q) {
        u16x4 hv, lv;
        #pragma unroll
        for (int j = 0; j < 4; ++j) {
            float a = T[orq + q * 4 + j][oc];
            unsigned short h = f2bf(a);
            hv[j] = h; lv[j] = f2bf(a - bf2f(h));
        }
        long long o = (long long)(c0 + oc) * R + r0 + orq + q * 4;
        *reinterpret_cast<u16x4*>(&oh[o]) = hv;
        *reinterpret_cast<u16x4*>(&ol[o]) = lv;
    }
}

// ---------------- fused split-precision bf16 GEMM (m97 structure) ----------------
// C = scale * (A @ B^T) + bias, where A ~ A0 + A1 (hi/lo), B ~ B0 + B1.
// Products fused in ONE K-loop: hh always, + h*l and l*h per NPROD.
// NPROD: 1 = A0*B0 | 2 = A0*(B0+B1) | 3 = (A0+A1)*(B0+B1) minus ll term
// All planes k-contiguous bf16: A[M][K] lda, Bt[N][K] ldb.
// 128x128 tile, BK=32, 4 waves, wave -> 64x64 quadrant (4x4 of 16x16x32).
// EPI: 0 f32 | 1 f32+bias | 2 bf16 | 3 QKV (Q^T,K^T hi/lo + V bf16; V blocks hh-only)
//      4 f32 atomicAdd (split-K)
// Split-K: blockIdx.z = (batch << sk_shift) | ks; K-slice = [ks*ks_size, ...).
template<int NPROD, int EPI>
__global__ __launch_bounds__(256)
void gemm_bt(const unsigned short* __restrict__ A0, const unsigned short* __restrict__ A1,
             const unsigned short* __restrict__ B0, const unsigned short* __restrict__ B1,
             int sk_shift, int ks_size,
             long long lda, long long ldb,
             long long sA, long long sB, long long sC,
             float* __restrict__ Cf, unsigned short* __restrict__ Cbf, long long ldc,
             const float* __restrict__ bias, float scale,
             unsigned short* __restrict__ qth, unsigned short* __restrict__ qtl,
             unsigned short* __restrict__ kth, unsigned short* __restrict__ ktl,
             unsigned short* __restrict__ vout)
{
    __shared__ __align__(16) unsigned short As[(NPROD >= 3) ? 2 : 1][128][32];
    __shared__ __align__(16) unsigned short Bs[(NPROD >= 2) ? 2 : 1][128][32];

    const int tid  = threadIdx.x;
    const int wave = tid >> 6, lane = tid & 63;
    const int m0 = blockIdx.y * 128, n0 = blockIdx.x * 128;
    const int bz = (int)(blockIdx.z >> sk_shift);
    const int ks = (int)(blockIdx.z & ((1u << sk_shift) - 1));
    const int kbeg = ks * ks_size, kend = kbeg + ks_size;
    const int wm = (wave >> 1) * 64, wn = (wave & 1) * 64;
    const int fr = lane & 15, kq = (lane >> 4) * 8;
    const int srow = lane >> 2, scol = (lane & 3) * 8;

    // V-columns of the QKV GEMM only need the hh product (block-uniform).
    const bool vonly  = (EPI == 3) && (n0 >= 2048);
    const bool asplit = (NPROD >= 3) && !vonly;
    const bool bsplit = (NPROD >= 2) && !vonly;

    const unsigned short* Ag0 = A0 + sA * bz + (long long)m0 * lda;
    const unsigned short* Ag1 = (NPROD >= 3) ? A1 + sA * bz + (long long)m0 * lda : nullptr;
    const unsigned short* Bg0 = B0 + sB * bz + (long long)n0 * ldb;
    const unsigned short* Bg1 = (NPROD >= 2) ? B1 + sB * bz + (long long)n0 * ldb : nullptr;

    char* const aBase = (char*)&As[0][0][0];
    char* const bBase = (char*)&Bs[0][0][0];

    f32x4 acc[4][4] = {};

    for (int k0 = kbeg; k0 < kend; k0 += 32) {
        #pragma unroll
        for (int i = 0; i < 2; ++i) {
            const int r = i * 64 + wave * 16 + srow;
            const long long ro = (long long)r * lda + k0 + scol;
            const long long rbo = (long long)r * ldb + k0 + scol;
            char* dstA = aBase + i * 4096 + wave * 1024;
            char* dstB = bBase + i * 4096 + wave * 1024;
            gload16(Ag0 + ro, dstA);
            gload16(Bg0 + rbo, dstB);
            if (asplit) gload16(Ag1 + ro, dstA + 8192);
            if (bsplit) gload16(Bg1 + rbo, dstB + 8192);
        }
        __syncthreads();   // compiler drains vmcnt/lgkmcnt

        bf16x8 ah[4], bh[4], al[4], bl[4];
        #pragma unroll
        for (int t = 0; t < 4; ++t) {
            ah[t] = *reinterpret_cast<const bf16x8*>(&As[0][wm + t * 16 + fr][kq]);
            bh[t] = *reinterpret_cast<const bf16x8*>(&Bs[0][wn + t * 16 + fr][kq]);
        }
        if (asplit)
            #pragma unroll
            for (int t = 0; t < 4; ++t)
                al[t] = *reinterpret_cast<const bf16x8*>(&As[NPROD >= 3 ? 1 : 0][wm + t * 16 + fr][kq]);
        if (bsplit)
            #pragma unroll
            for (int t = 0; t < 4; ++t)
                bl[t] = *reinterpret_cast<const bf16x8*>(&Bs[NPROD >= 2 ? 1 : 0][wn + t * 16 + fr][kq]);

        if (asplit)
            #pragma unroll
            for (int mi = 0; mi < 4; ++mi)
                #pragma unroll
                for (int ni = 0; ni < 4; ++ni)
                    acc[mi][ni] = __builtin_amdgcn_mfma_f32_16x16x32_bf16(al[mi], bh[ni], acc[mi][ni], 0, 0, 0);
        if (bsplit)
            #pragma unroll
            for (int mi = 0; mi < 4; ++mi)
                #pragma unroll
                for (int ni = 0; ni < 4; ++ni)
                    acc[mi][ni] = __builtin_amdgcn_mfma_f32_16x16x32_bf16(ah[mi], bl[ni], acc[mi][ni], 0, 0, 0);
        #pragma unroll
        for (int mi = 0; mi < 4; ++mi)
            #pragma unroll
            for (int ni = 0; ni < 4; ++ni)
                acc[mi][ni] = __builtin_amdgcn_mfma_f32_16x16x32_bf16(ah[mi], bh[ni], acc[mi][ni], 0, 0, 0);
        __syncthreads();
    }

    // epilogue: D[row=(lane>>4)*4+rr][col=lane&15]
    const int rb4 = (lane >> 4) * 4;
    #pragma unroll
    for (int mi = 0; mi < 4; ++mi) {
        const int rloc = wm + mi * 16 + rb4;
        #pragma unroll
        for (int ni = 0; ni < 4; ++ni) {
            const int c = n0 + wn + ni * 16 + fr;
            float bv = (EPI == 1 || EPI == 3) ? bias[c] : 0.0f;
            float v[4];
            #pragma unroll
            for (int rr = 0; rr < 4; ++rr) v[rr] = acc[mi][ni][rr] * scale + bv;

            if (EPI == 0 || EPI == 1) {
                long long base = sC * bz + (long long)(m0 + rloc) * ldc + c;
                #pragma unroll
                for (int rr = 0; rr < 4; ++rr) Cf[base + (long long)rr * ldc] = v[rr];
            } else if (EPI == 4) {
                long long base = sC * bz + (long long)(m0 + rloc) * ldc + c;
                #pragma unroll
                for (int rr = 0; rr < 4; ++rr) atomicAdd(&Cf[base + (long long)rr * ldc], v[rr]);
            } else if (EPI == 2) {
                long long base = sC * bz + (long long)(m0 + rloc) * ldc + c;
                #pragma unroll
                for (int rr = 0; rr < 4; ++rr) Cbf[base + (long long)rr * ldc] = f2bf(v[rr]);
            } else {
                const int m = m0 + rloc;          // 0..8191 (2-batch chunk)
                const int bloc = m >> 12;
                const int nb = m & 4095;
                const int seg = n0 >> 10;         // block-uniform: 0=Q 1=K 2=V
                const int lc = c & 1023;
                if (seg == 2) {
                    #pragma unroll
                    for (int rr = 0; rr < 4; ++rr)
                        vout[(long long)bloc * 4194304 + (long long)(nb + rr) * 1024 + lc] = f2bf(v[rr]);
                } else {
                    u16x4 hv, lv;
                    #pragma unroll
                    for (int rr = 0; rr < 4; ++rr) {
                        unsigned short h = f2bf(v[rr]);
                        hv[rr] = h; lv[rr] = f2bf(v[rr] - bf2f(h));
                    }
                    long long o = (long long)bloc * 4194304 + (long long)lc * 4096 + nb;
                    unsigned short* ph = (seg == 0) ? qth : kth;
                    unsigned short* pl = (seg == 0) ? qtl : ktl;
                    *reinterpret_cast<u16x4*>(&ph[o]) = hv;
                    *reinterpret_cast<u16x4*>(&pl[o]) = lv;
                }
            }
        }
    }
}

// ---------------- row softmax: 1024 fp32 -> 1024 bf16 ----------------
__global__ __launch_bounds__(256)
void softmax_rows_1024(const float* __restrict__ in, unsigned short* __restrict__ out)
{
    const int tid = threadIdx.x;
    const int wave = tid >> 6, lane = tid & 63;
    const long long rowoff = (long long)blockIdx.x * 1024;
    float4 v = reinterpret_cast<const float4*>(in + rowoff)[tid];

    float mx = fmaxf(fmaxf(v.x, v.y), fmaxf(v.z, v.w));
    #pragma unroll
    for (int o = 32; o > 0; o >>= 1) mx = fmaxf(mx, __shfl_xor(mx, o));
    __shared__ float rmax[4];
    if (lane == 0) rmax[wave] = mx;
    __syncthreads();
    mx = fmaxf(fmaxf(rmax[0], rmax[1]), fmaxf(rmax[2], rmax[3]));

    float e0 = expf(v.x - mx), e1 = expf(v.y - mx), e2 = expf(v.z - mx), e3 = expf(v.w - mx);
    float s = e0 + e1 + e2 + e3;
    #pragma unroll
    for (int o = 32; o > 0; o >>= 1) s += __shfl_xor(s, o);
    __shared__ float rsum[4];
    if (lane == 0) rsum[wave] = s;
    __syncthreads();
    s = rsum[0] + rsum[1] + rsum[2] + rsum[3];
    float inv = 1.0f / s;

    u16x4 o4;
    o4[0] = f2bf(e0 * inv); o4[1] = f2bf(e1 * inv);
    o4[2] = f2bf(e2 * inv); o4[3] = f2bf(e3 * inv);
    *reinterpret_cast<u16x4*>(out + rowoff + tid * 4) = o4;
}

extern "C" void kernel_launch(void* const* d_in, const int* in_sizes, int n_in,
                              void* d_out, int out_size, void* d_ws, size_t ws_size,
                              hipStream_t stream)
{
    const float* x    = (const float*)d_in[0];  // (4,4096,1024)
    const float* Wqkv = (const float*)d_in[1];  // (1024,3072)
    const float* bqkv = (const float*)d_in[2];  // (3072,)
    const float* Wout = (const float*)d_in[3];  // (1024,1024)
    const float* bout = (const float*)d_in[4];  // (1024,)
    float* out = (float*)d_out;                 // (4,4096,1024) fp32

    // ---- workspace (peak 201,326,592 B == proven-safe) ----
    char* ws = (char*)d_ws;
    unsigned short* xh   = (unsigned short*)(ws);              // 33,554,432
    unsigned short* xl   = (unsigned short*)(ws + 33554432);   // 33,554,432
    unsigned short* Wqh  = (unsigned short*)(ws + 67108864);   //  6,291,456 (3072x1024)
    unsigned short* Wql  = (unsigned short*)(ws + 73400320);   //  6,291,456
    unsigned short* Woh  = (unsigned short*)(ws + 79691776);   //  2,097,152 (1024x1024)
    unsigned short* Wol  = (unsigned short*)(ws + 81788928);   //  2,097,152
    unsigned short* V    = (unsigned short*)(ws + 83886080);   // 33,554,432 (4,4096,1024) bf16
    unsigned short* Qth  = (unsigned short*)(ws + 117440512);  // 16,777,216 (2,1024,4096)
    unsigned short* Qtl  = (unsigned short*)(ws + 134217728);
    unsigned short* Kth  = (unsigned short*)(ws + 150994944);
    unsigned short* Ktl  = (unsigned short*)(ws + 167772160);
    float*          dots = (float*)(ws + 184549376);           // 16,777,216 (4,1024,1024) f32
    unsigned short* attn = (unsigned short*)(ws);              //  8,388,608 (overlays xh; dead)
    unsigned short* omid = (unsigned short*)(ws + 8388608);    // 33,554,432 (overlays x; dead)

    // dots is accumulated atomically (split-K) -> zero it first
    zero_f32<<<dim3(2048), dim3(256), 0, stream>>>(dots, 1048576);

    // converts
    split_f32<<<dim3(2048), dim3(256), 0, stream>>>(x, xh, xl, 2097152);
    transpose_split<<<dim3(48, 16), dim3(256), 0, stream>>>(Wqkv, Wqh, Wql, 1024, 3072);
    transpose_split<<<dim3(16, 16), dim3(256), 0, stream>>>(Wout, Woh, Wol, 1024, 1024);

    for (int c = 0; c < 2; ++c) {
        // 1) qkv chunk: fused (xh+xl)@(Wh+Wl) -> Q^T/K^T hi+lo, V bf16 (V: hh only)
        gemm_bt<3, 3><<<dim3(24, 64, 1), dim3(256), 0, stream>>>(
            xh + c * 8388608, xl + c * 8388608, Wqh, Wql,
            0, 1024, 1024LL, 1024LL, 0LL, 0LL, 0LL,
            nullptr, nullptr, 0LL, bqkv, 1.0f,
            Qth, Qtl, Kth, Ktl, V + c * 8388608);

        // 2) dots chunk: fused 3-product, split-K x4, atomic f32
        gemm_bt<3, 4><<<dim3(8, 8, 8), dim3(256), 0, stream>>>(
            Qth, Qtl, Kth, Ktl,
            2, 1024, 4096LL, 4096LL, 4194304LL, 4194304LL, 1048576LL,
            dots + c * 2097152, nullptr, 1024LL, nullptr, 0.125f,
            nullptr, nullptr, nullptr, nullptr, nullptr);
    }

    // 3) softmax (all 4096 rows) -> attn bf16
    softmax_rows_1024<<<dim3(4096), dim3(256), 0, stream>>>(dots, attn);

    // 4) omid[b][f][n] = attn[b] @ V[b]^T  (M=1024, N=4096, K=1024) -> bf16
    gemm_bt<1, 2><<<dim3(32, 8, 4), dim3(256), 0, stream>>>(
        attn, nullptr, V, nullptr,
        0, 1024, 1024LL, 1024LL, 1048576LL, 4194304LL, 4194304LL,
        nullptr, omid, 4096LL, nullptr, 1.0f,
        nullptr, nullptr, nullptr, nullptr, nullptr);

    // 5) out = omid_flat(16384x1024) @ (Woh+Wol)^T + bout -> f32
    gemm_bt<2, 1><<<dim3(8, 128, 1), dim3(256), 0, stream>>>(
        omid, nullptr, Woh, Wol,
        0, 1024, 1024LL, 1024LL, 0LL, 0LL, 0LL,
        out, nullptr, 1024LL, bout, 1.0f,
        nullptr, nullptr, nullptr, nullptr, nullptr);
}

// Round 7
// 408.269 us; speedup vs baseline: 4.6353x; 1.5283x over previous
//
#include <hip/hip_runtime.h>
#include <hip/hip_bf16.h>

typedef _Float16 f16x8 __attribute__((ext_vector_type(8)));
typedef float f32x4 __attribute__((ext_vector_type(4)));
typedef unsigned short u16x4 __attribute__((ext_vector_type(4)));
typedef unsigned short u16x8 __attribute__((ext_vector_type(8)));

__device__ __forceinline__ unsigned short f2h(float f) {
    _Float16 h = (_Float16)f;
    union { _Float16 h; unsigned short u; } v; v.h = h;
    return v.u;
}

// async global->LDS, 16B per lane. LDS dest = wave-uniform base + lane*16.
__device__ __forceinline__ void gload16(const void* g, void* s) {
    __builtin_amdgcn_global_load_lds((const __attribute__((address_space(1))) void*)g,
                                     (__attribute__((address_space(3))) void*)s, 16, 0, 0);
}

// ---------------- zero fp32 buffer ----------------
__global__ __launch_bounds__(256)
void zero_f32(float* __restrict__ p, int n4) {
    int i = blockIdx.x * 256 + threadIdx.x, st = gridDim.x * 256;
    for (; i < n4; i += st)
        reinterpret_cast<float4*>(p)[i] = make_float4(0.f, 0.f, 0.f, 0.f);
}

// ---------------- fp32 -> fp16 convert ----------------
__global__ __launch_bounds__(256)
void cvt_f32_f16(const float* __restrict__ in, unsigned short* __restrict__ out, int n8) {
    int i = blockIdx.x * 256 + threadIdx.x, st = gridDim.x * 256;
    for (; i < n8; i += st) {
        float4 v0 = reinterpret_cast<const float4*>(in)[2 * i];
        float4 v1 = reinterpret_cast<const float4*>(in)[2 * i + 1];
        float a[8] = {v0.x, v0.y, v0.z, v0.w, v1.x, v1.y, v1.z, v1.w};
        u16x8 h;
        #pragma unroll
        for (int j = 0; j < 8; ++j) h[j] = f2h(a[j]);
        reinterpret_cast<u16x8*>(out)[i] = h;
    }
}

// ---------------- W (R x C fp32) -> W^T fp16 (C x R) ----------------
__global__ __launch_bounds__(256)
void transpose_cvt(const float* __restrict__ in, unsigned short* __restrict__ ot,
                   int R, int C) {
    __shared__ float T[64][65];
    const int r0 = blockIdx.y * 64, c0 = blockIdx.x * 64;
    const int t = threadIdx.x;
    const int lr = t >> 2, lcq = (t & 3) * 16;
    #pragma unroll
    for (int q = 0; q < 4; ++q) {
        float4 v = *reinterpret_cast<const float4*>(&in[(long long)(r0 + lr) * C + c0 + lcq + q * 4]);
        T[lr][lcq + q * 4 + 0] = v.x; T[lr][lcq + q * 4 + 1] = v.y;
        T[lr][lcq + q * 4 + 2] = v.z; T[lr][lcq + q * 4 + 3] = v.w;
    }
    __syncthreads();
    const int oc = t >> 2, orq = (t & 3) * 16;
    #pragma unroll
    for (int q = 0; q < 4; ++q) {
        u16x4 hv;
        #pragma unroll
        for (int j = 0; j < 4; ++j) hv[j] = f2h(T[orq + q * 4 + j][oc]);
        long long o = (long long)(c0 + oc) * R + r0 + orq + q * 4;
        *reinterpret_cast<u16x4*>(&ot[o]) = hv;
    }
}

// ---------------- fp16 MFMA GEMM (m97 structure) ----------------
// C = scale * (A @ B^T) + bias. A[M][K] lda, Bt[N][K] ldb, k-contiguous fp16.
// 128x128 tile, BK=32, 4 waves, wave -> 64x64 quadrant (4x4 of 16x16x32).
// EPI: 1 f32+bias | 2 f16 | 3 QKV (Q^T,K^T f16 transposed + V f16; bias)
//      4 f32 atomicAdd (split-K)
// Split-K: blockIdx.z = (batch << sk_shift) | ks; K-slice = [ks*ks_size, +ks_size).
template<int EPI>
__global__ __launch_bounds__(256)
void gemm_f16(const unsigned short* __restrict__ A, const unsigned short* __restrict__ B,
              int sk_shift, int ks_size,
              long long lda, long long ldb,
              long long sA, long long sB, long long sC,
              float* __restrict__ Cf, unsigned short* __restrict__ Ch, long long ldc,
              const float* __restrict__ bias, float scale,
              unsigned short* __restrict__ qt, unsigned short* __restrict__ kt,
              unsigned short* __restrict__ vout)
{
    __shared__ __align__(16) unsigned short As[128][32];
    __shared__ __align__(16) unsigned short Bs[128][32];

    const int tid  = threadIdx.x;
    const int wave = tid >> 6, lane = tid & 63;
    const int m0 = blockIdx.y * 128, n0 = blockIdx.x * 128;
    const int bz = (int)(blockIdx.z >> sk_shift);
    const int ks = (int)(blockIdx.z & ((1u << sk_shift) - 1));
    const int kbeg = ks * ks_size, kend = kbeg + ks_size;
    const int wm = (wave >> 1) * 64, wn = (wave & 1) * 64;
    const int fr = lane & 15, kq = (lane >> 4) * 8;
    const int srow = lane >> 2, scol = (lane & 3) * 8;

    const unsigned short* Ag = A + sA * bz + (long long)m0 * lda;
    const unsigned short* Bg = B + sB * bz + (long long)n0 * ldb;
    char* const aBase = (char*)&As[0][0];
    char* const bBase = (char*)&Bs[0][0];

    f32x4 acc[4][4] = {};

    for (int k0 = kbeg; k0 < kend; k0 += 32) {
        #pragma unroll
        for (int i = 0; i < 2; ++i) {
            const int r = i * 64 + wave * 16 + srow;
            gload16(Ag + (long long)r * lda + k0 + scol, aBase + i * 4096 + wave * 1024);
            gload16(Bg + (long long)r * ldb + k0 + scol, bBase + i * 4096 + wave * 1024);
        }
        __syncthreads();   // compiler drains vmcnt/lgkmcnt

        f16x8 af[4], bf[4];
        #pragma unroll
        for (int t = 0; t < 4; ++t) {
            af[t] = *reinterpret_cast<const f16x8*>(&As[wm + t * 16 + fr][kq]);
            bf[t] = *reinterpret_cast<const f16x8*>(&Bs[wn + t * 16 + fr][kq]);
        }
        #pragma unroll
        for (int mi = 0; mi < 4; ++mi)
            #pragma unroll
            for (int ni = 0; ni < 4; ++ni)
                acc[mi][ni] = __builtin_amdgcn_mfma_f32_16x16x32_f16(af[mi], bf[ni], acc[mi][ni], 0, 0, 0);
        __syncthreads();
    }

    // epilogue: D[row=(lane>>4)*4+rr][col=lane&15]
    const int rb4 = (lane >> 4) * 4;
    #pragma unroll
    for (int mi = 0; mi < 4; ++mi) {
        const int rloc = wm + mi * 16 + rb4;
        #pragma unroll
        for (int ni = 0; ni < 4; ++ni) {
            const int c = n0 + wn + ni * 16 + fr;
            float bv = (EPI == 1 || EPI == 3) ? bias[c] : 0.0f;
            float v[4];
            #pragma unroll
            for (int rr = 0; rr < 4; ++rr) v[rr] = acc[mi][ni][rr] * scale + bv;

            if (EPI == 1) {
                long long base = sC * bz + (long long)(m0 + rloc) * ldc + c;
                #pragma unroll
                for (int rr = 0; rr < 4; ++rr) Cf[base + (long long)rr * ldc] = v[rr];
            } else if (EPI == 4) {
                long long base = sC * bz + (long long)(m0 + rloc) * ldc + c;
                #pragma unroll
                for (int rr = 0; rr < 4; ++rr) atomicAdd(&Cf[base + (long long)rr * ldc], v[rr]);
            } else if (EPI == 2) {
                long long base = sC * bz + (long long)(m0 + rloc) * ldc + c;
                #pragma unroll
                for (int rr = 0; rr < 4; ++rr) Ch[base + (long long)rr * ldc] = f2h(v[rr]);
            } else {
                const int m = m0 + rloc;          // 0..16383
                const int bloc = m >> 12;         // batch
                const int nb = m & 4095;          // token
                const int seg = n0 >> 10;         // block-uniform: 0=Q 1=K 2=V
                const int lc = c & 1023;
                if (seg == 2) {
                    #pragma unroll
                    for (int rr = 0; rr < 4; ++rr)
                        vout[(long long)bloc * 4194304 + (long long)(nb + rr) * 1024 + lc] = f2h(v[rr]);
                } else {
                    u16x4 hv;
                    #pragma unroll
                    for (int rr = 0; rr < 4; ++rr) hv[rr] = f2h(v[rr]);
                    long long o = (long long)bloc * 4194304 + (long long)lc * 4096 + nb;
                    unsigned short* pt = (seg == 0) ? qt : kt;
                    *reinterpret_cast<u16x4*>(&pt[o]) = hv;
                }
            }
        }
    }
}

// ---------------- row softmax: 1024 fp32 -> 1024 fp16 ----------------
__global__ __launch_bounds__(256)
void softmax_rows_1024(const float* __restrict__ in, unsigned short* __restrict__ out)
{
    const int tid = threadIdx.x;
    const int wave = tid >> 6, lane = tid & 63;
    const long long rowoff = (long long)blockIdx.x * 1024;
    float4 v = reinterpret_cast<const float4*>(in + rowoff)[tid];

    float mx = fmaxf(fmaxf(v.x, v.y), fmaxf(v.z, v.w));
    #pragma unroll
    for (int o = 32; o > 0; o >>= 1) mx = fmaxf(mx, __shfl_xor(mx, o));
    __shared__ float rmax[4];
    if (lane == 0) rmax[wave] = mx;
    __syncthreads();
    mx = fmaxf(fmaxf(rmax[0], rmax[1]), fmaxf(rmax[2], rmax[3]));

    float e0 = expf(v.x - mx), e1 = expf(v.y - mx), e2 = expf(v.z - mx), e3 = expf(v.w - mx);
    float s = e0 + e1 + e2 + e3;
    #pragma unroll
    for (int o = 32; o > 0; o >>= 1) s += __shfl_xor(s, o);
    __shared__ float rsum[4];
    if (lane == 0) rsum[wave] = s;
    __syncthreads();
    s = rsum[0] + rsum[1] + rsum[2] + rsum[3];
    float inv = 1.0f / s;

    u16x4 o4;
    o4[0] = f2h(e0 * inv); o4[1] = f2h(e1 * inv);
    o4[2] = f2h(e2 * inv); o4[3] = f2h(e3 * inv);
    *reinterpret_cast<u16x4*>(out + rowoff + tid * 4) = o4;
}

extern "C" void kernel_launch(void* const* d_in, const int* in_sizes, int n_in,
                              void* d_out, int out_size, void* d_ws, size_t ws_size,
                              hipStream_t stream)
{
    const float* x    = (const float*)d_in[0];  // (4,4096,1024)
    const float* Wqkv = (const float*)d_in[1];  // (1024,3072)
    const float* bqkv = (const float*)d_in[2];  // (3072,)
    const float* Wout = (const float*)d_in[3];  // (1024,1024)
    const float* bout = (const float*)d_in[4];  // (1024,)
    float* out = (float*)d_out;                 // (4,4096,1024) fp32

    // ---- workspace (peak 201,326,592 B == proven-safe) ----
    char* ws = (char*)d_ws;
    unsigned short* xf   = (unsigned short*)(ws);              // 33,554,432 (4,4096,1024) f16
    unsigned short* Wq16 = (unsigned short*)(ws + 33554432);   //  6,291,456 (3072,1024) f16 W^T
    unsigned short* Wo16 = (unsigned short*)(ws + 39845888);   //  2,097,152 (1024,1024) f16 W^T
    unsigned short* Qt   = (unsigned short*)(ws + 41943040);   // 33,554,432 (4,1024,4096) f16
    unsigned short* Kt   = (unsigned short*)(ws + 75497472);   // 33,554,432
    unsigned short* V    = (unsigned short*)(ws + 109051904);  // 33,554,432 (4,4096,1024) f16
    float*          dots = (float*)(ws + 142606336);           // 16,777,216 (4,1024,1024) f32
    unsigned short* attn = (unsigned short*)(ws + 159383552);  //  8,388,608 (4,1024,1024) f16
    unsigned short* omid = (unsigned short*)(ws + 167772160);  // 33,554,432 (4,1024,4096) f16

    // dots accumulated atomically (split-K) -> zero first
    zero_f32<<<dim3(2048), dim3(256), 0, stream>>>(dots, 1048576);

    // converts
    cvt_f32_f16<<<dim3(2048), dim3(256), 0, stream>>>(x, xf, 2097152);
    transpose_cvt<<<dim3(48, 16), dim3(256), 0, stream>>>(Wqkv, Wq16, 1024, 3072);
    transpose_cvt<<<dim3(16, 16), dim3(256), 0, stream>>>(Wout, Wo16, 1024, 1024);

    // 1) qkv = x @ Wqkv + bqkv -> Q^T, K^T (transposed f16) + V f16  (M=16384, N=3072, K=1024)
    gemm_f16<3><<<dim3(24, 128, 1), dim3(256), 0, stream>>>(
        xf, Wq16, 0, 1024,
        1024LL, 1024LL, 0LL, 0LL, 0LL,
        nullptr, nullptr, 0LL, bqkv, 1.0f,
        Qt, Kt, V);

    // 2) dots[b] = 0.125 * Q^T K  (M=N=1024, K=4096), split-K x4, atomic f32
    gemm_f16<4><<<dim3(8, 8, 16), dim3(256), 0, stream>>>(
        Qt, Kt, 2, 1024,
        4096LL, 4096LL, 4194304LL, 4194304LL, 1048576LL,
        dots, nullptr, 1024LL, nullptr, 0.125f,
        nullptr, nullptr, nullptr);

    // 3) softmax over g -> attn f16
    softmax_rows_1024<<<dim3(4096), dim3(256), 0, stream>>>(dots, attn);

    // 4) omid[b][f][n] = attn[b] @ V[b]^T  (M=1024, N=4096, K=1024) -> f16
    gemm_f16<2><<<dim3(32, 8, 4), dim3(256), 0, stream>>>(
        attn, V, 0, 1024,
        1024LL, 1024LL, 1048576LL, 4194304LL, 4194304LL,
        nullptr, omid, 4096LL, nullptr, 1.0f,
        nullptr, nullptr, nullptr);

    // 5) out = omid_flat(16384x1024) @ Wout^T + bout -> f32
    gemm_f16<1><<<dim3(8, 128, 1), dim3(256), 0, stream>>>(
        omid, Wo16, 0, 1024,
        1024LL, 1024LL, 0LL, 0LL, 0LL,
        out, nullptr, 1024LL, bout, 1.0f,
        nullptr, nullptr, nullptr);
}